// Round 17
// baseline (160.614 us; speedup 1.0000x reference)
//
#include <hip/hip_runtime.h>

typedef unsigned short u16;
typedef __attribute__((ext_vector_type(8))) short s16x8;
typedef __attribute__((ext_vector_type(4))) float f32x4;
typedef __attribute__((ext_vector_type(4))) int   i32x4;
typedef __attribute__((ext_vector_type(2))) int   i32x2;
typedef __attribute__((ext_vector_type(4))) unsigned short u16x4;

// ---------------- workspace layout (bytes) ----------------
constexpr size_t OFF_XB   = 0;                     // bf16 x [2048][1024]; later VEPI
constexpr size_t OFF_WQB  = OFF_XB   + 4194304;    // bf16 Wq         [1024][1024]
constexpr size_t OFF_WKB  = OFF_WQB  + 2097152;    // bf16 Wk         [512][1024]
constexpr size_t OFF_WVB  = OFF_WKB  + 1048576;    // bf16 Wv         [512][1024]
constexpr size_t OFF_WOB  = OFF_WVB  + 1048576;    // bf16 Wo         [1024][1024]
constexpr size_t OFF_W1T  = OFF_WOB  + 2097152;    // bf16 W1T [384][1024]; later DP
constexpr size_t OFF_W2T  = OFF_W1T  + 786432;     // bf16 w2T        [1024][64]
constexpr size_t OFF_A2T  = OFF_W2T  + 131072;     // bf16 a2T        [1024][64]
constexpr size_t OFF_V2T  = OFF_A2T  + 131072;     // bf16 v2T        [1024][32]
constexpr size_t OFF_G2T  = OFF_V2T  + 65536;      // bf16 g2T        [1024][160]
constexpr size_t OFF_KQF  = OFF_G2T  + 327680;     // f32 k-proj      [2048][512]
constexpr size_t OFF_VQF  = OFF_KQF  + 4194304;    // f32 v-proj      [2048][512]
constexpr size_t OFF_URAW = OFF_VQF  + 4194304;    // (dead)
constexpr size_t OFF_UB   = OFF_URAW + 2621440;    // bf16 stage1 act [2048][384]
constexpr size_t OFF_S2A  = OFF_UB   + 1572864;    // f32 iclr        [2048][1024]
constexpr size_t OFF_S2V  = OFF_S2A  + 8388608;    // f32 vmix        [2048][1024]
constexpr size_t OFF_GBUF = OFF_S2V  + 8388608;    // f32 gate        [2048][1024]
constexpr size_t OFF_SEQ  = OFF_GBUF + 8388608;    // chunks [2048][24576B]; later records
constexpr size_t OFF_YBUF = OFF_SEQ  + 50331648;   // f32 y   [2][16][1024][64]
constexpr size_t OFF_XGB  = OFF_YBUF + 8388608;    // bf16 xn*g       [2048][1024]

// SEQ chunk payload (first 14336B of each 24576B slot), per t-row stride 896:
//  +0 r bf16[64] | +128 k | +256 v | +384 a | +512 b | +640 decay f32[64]
// record overlay (pre overwrites its OWN chunk): 0 Q(8192) | 8192 G(2048) |
//  10240 pL f32[64] | 10496 + w*2560 { c[jt4][lane]x8B (2048) | Yloc (512) }
constexpr size_t OFF_VEPI = OFF_XB;                // bf16 v rows (XB dead after gemm0)
constexpr size_t OFF_DP   = OFF_W1T;               // f32 dp (W1T dead after gemm0)

__device__ __forceinline__ u16 f2bf(float f){
  unsigned int u = __builtin_bit_cast(unsigned int, f);
  u = u + 0x7fffu + ((u >> 16) & 1u);
  return (u16)(u >> 16);
}
__device__ __forceinline__ int pk2(float a, float b){
  return (int)((unsigned)f2bf(a) | ((unsigned)f2bf(b) << 16));
}
__device__ __forceinline__ int cvtpk(float a, float b){
  int r;
  asm("v_cvt_pk_bf16_f32 %0, %1, %2" : "=v"(r) : "v"(a), "v"(b));
  return r;
}
__device__ __forceinline__ float bf2f(u16 h){
  return __builtin_bit_cast(float, ((unsigned)h) << 16);
}
__device__ __forceinline__ f32x4 cvt4(i32x2 v){
  unsigned a=(unsigned)v[0], b=(unsigned)v[1];
  f32x4 r;
  r[0]=__builtin_bit_cast(float, a<<16);
  r[1]=__builtin_bit_cast(float, a&0xffff0000u);
  r[2]=__builtin_bit_cast(float, b<<16);
  r[3]=__builtin_bit_cast(float, b&0xffff0000u);
  return r;
}

__device__ __forceinline__ void gload_lds16(const float* g, float* l){
  __builtin_amdgcn_global_load_lds((const __attribute__((address_space(1))) void*)g,
                                   (__attribute__((address_space(3))) void*)l, 16, 0, 0);
}
__device__ __forceinline__ void gload_lds16u(const u16* g, u16* l){
  __builtin_amdgcn_global_load_lds((const __attribute__((address_space(1))) void*)g,
                                   (__attribute__((address_space(3))) void*)l, 16, 0, 0);
}

// ---------------- prep: vectorized convert + transposes + v_first passthrough ----------------
constexpr size_t N_XB=2097152, N_WQ=1048576, N_WK=524288, N_WV=524288, N_WO=1048576,
  N_W1T=393216, N_W2T=65536, N_A2T=65536, N_V2T=32768, N_G2T=163840, N_VF=2097152;
constexpr size_t NV_BULK = (N_XB+N_WQ+N_WK+N_WV+N_WO)/4;   // vectorized bf16 copies
constexpr size_t NV_VF   = N_VF/4;                          // vectorized f32 copy
constexpr size_t N_SCAL  = N_W1T+N_W2T+N_A2T+N_V2T+N_G2T;   // scalar transposes
constexpr size_t PREP_TOT = NV_BULK + NV_VF + N_SCAL;

__global__ __launch_bounds__(256) void prep_kernel(char* ws, const float* x, const float* vfirst,
  const float* w1, const float* w2, const float* a1, const float* a2,
  const float* v1, const float* v2, const float* g1, const float* g2,
  const float* Wq, const float* Wk, const float* Wv, const float* Wo, float* dout)
{
  u16* XB=(u16*)(ws+OFF_XB); u16* WQB=(u16*)(ws+OFF_WQB); u16* WKB=(u16*)(ws+OFF_WKB);
  u16* WVB=(u16*)(ws+OFF_WVB); u16* WOB=(u16*)(ws+OFF_WOB); u16* W1T=(u16*)(ws+OFF_W1T);
  u16* W2T=(u16*)(ws+OFF_W2T); u16* A2T=(u16*)(ws+OFF_A2T); u16* V2T=(u16*)(ws+OFF_V2T);
  u16* G2T=(u16*)(ws+OFF_G2T);
  for (size_t idx=(size_t)blockIdx.x*256+threadIdx.x; idx<PREP_TOT; idx+=(size_t)gridDim.x*256){
    size_t r = idx;
    if (r < NV_BULK){
      size_t e = r*4;
      const float* src; u16* dst;
      if (e < N_XB){ src=x+e; dst=XB+e; }
      else { e-=N_XB;
        if (e < N_WQ){ src=Wq+e; dst=WQB+e; }
        else { e-=N_WQ;
          if (e < N_WK){ src=Wk+e; dst=WKB+e; }
          else { e-=N_WK;
            if (e < N_WV){ src=Wv+e; dst=WVB+e; }
            else { e-=N_WV; src=Wo+e; dst=WOB+e; }
          }
        }
      }
      f32x4 v=*(const f32x4*)src;
      u16x4 o; o[0]=f2bf(v[0]); o[1]=f2bf(v[1]); o[2]=f2bf(v[2]); o[3]=f2bf(v[3]);
      *(u16x4*)dst=o;
      continue;
    }
    r -= NV_BULK;
    if (r < NV_VF){
      size_t e=r*4;
      *(f32x4*)(dout + 2228224 + e) = *(const f32x4*)(vfirst + e);
      continue;
    }
    r -= NV_VF;
    if (r < N_W1T){
      int n=(int)(r>>10), k=(int)(r&1023); float v=0.f;
      if (n<64) v=w1[(size_t)k*64+n];
      else if (n<128) v=a1[(size_t)k*64+(n-64)];
      else if (n<160) v=v1[(size_t)k*32+(n-128)];
      else if (n<320) v=g1[(size_t)k*160+(n-160)];
      W1T[r]=f2bf(v); continue; } r-=N_W1T;
    if (r < N_W2T){ int c=(int)(r>>6), d=(int)(r&63); W2T[r]=f2bf(w2[(size_t)d*1024+c]); continue; } r-=N_W2T;
    if (r < N_A2T){ int c=(int)(r>>6), d=(int)(r&63); A2T[r]=f2bf(a2[(size_t)d*1024+c]); continue; } r-=N_A2T;
    if (r < N_V2T){ int c=(int)(r>>5), d=(int)(r&31); V2T[r]=f2bf(v2[(size_t)d*1024+c]); continue; } r-=N_V2T;
    { int c=(int)(r/160), d=(int)(r%160); G2T[r]=f2bf(g2[(size_t)d*1024+c]); }
  }
}

// ---------------- unified NT bf16 MFMA GEMM: C[m][n] = sum_k A[m][k]*B[n][k] ----------------
// 64x128 tile, 4 waves (2Mx2N), LDS 24KB; global_load_lds staging with XOR chunk swizzle.
__global__ __launch_bounds__(256) void gemm_kernel(int phase, char* ws,
  const float* w0b, const float* a0b, const float* v0b, float* dout)
{
  const u16* A; const u16* Bw;
  float* outF=nullptr; const float* bias=nullptr;
  char* SEQc=(char*)(ws+OFF_SEQ);
  u16* UBp=(u16*)(ws+OFF_UB);
  int lda=0, ldb=0, K=0, ldc=0, Nlim=1024, col0=0, outMode=0;
  int y = blockIdx.y;
  if (phase==0){
    A=(const u16*)(ws+OFF_XB); lda=1024; K=1024;
    if (y<8)      { Bw=(const u16*)(ws+OFF_WQB); ldb=1024; col0=y*128;       outMode=1; }
    else if (y<12){ Bw=(const u16*)(ws+OFF_WKB); ldb=1024; col0=(y-8)*128;   outF=(float*)(ws+OFF_KQF); ldc=512; Nlim=512; }
    else if (y<16){ Bw=(const u16*)(ws+OFF_WVB); ldb=1024; col0=(y-12)*128;  outF=(float*)(ws+OFF_VQF); ldc=512; Nlim=512; }
    else          { Bw=(const u16*)(ws+OFF_W1T); ldb=1024; col0=(y-16)*128;  outMode=4; Nlim=320; }
  } else if (phase==1){
    int seg=y>>3; col0=(y&7)*128;
    const int Ks[4]={64,64,32,160};
    const int Ao[4]={0,64,128,160};
    K=Ks[seg]; lda=384; ldb=K;
    A=(const u16*)(ws+OFF_UB) + Ao[seg];
    if (seg==0)     { Bw=(const u16*)(ws+OFF_W2T); outMode=2; bias=w0b; }
    else if (seg==1){ Bw=(const u16*)(ws+OFF_A2T); outMode=3; bias=a0b; outF=(float*)(ws+OFF_S2A); ldc=1024; }
    else if (seg==2){ Bw=(const u16*)(ws+OFF_V2T); outMode=3; bias=v0b; outF=(float*)(ws+OFF_S2V); ldc=1024; }
    else            { Bw=(const u16*)(ws+OFF_G2T); outF=(float*)(ws+OFF_GBUF); ldc=1024; }
  } else {
    A=(const u16*)(ws+OFF_XGB); lda=1024; K=1024;
    Bw=(const u16*)(ws+OFF_WOB); ldb=1024; col0=y*128; outF=dout; ldc=1024;
  }
  int m0 = blockIdx.x*64;
  __shared__ __align__(16) u16 As[2][2048];   // 64 x 32
  __shared__ __align__(16) u16 Bs[2][4096];   // 128 x 32
  int tid=threadIdx.x, l=tid&63, wv=tid>>6, wm=wv>>1, wn=wv&1;

  int cswz = (l&3) ^ ((l>>3)&3);
  int srA = wv*16 + (l>>2);
  int srB = wv*32 + (l>>2);
  const u16* aP0 = A  + (size_t)(m0+srA)*lda       + cswz*8;
  const u16* bP0 = Bw + (size_t)(col0+srB)*ldb     + cswz*8;
  const u16* bP1 = Bw + (size_t)(col0+srB+16)*ldb  + cswz*8;

  f32x4 acc[2][4];
  #pragma unroll
  for (int i=0;i<2;i++)
    #pragma unroll
    for (int j=0;j<4;j++) acc[i][j]=(f32x4){0.f,0.f,0.f,0.f};

#define GSTAGE(b,k0) do{                                   \
    gload_lds16u(aP0 + (k0), &As[b][wv*512]);              \
    gload_lds16u(bP0 + (k0), &Bs[b][wv*1024]);             \
    gload_lds16u(bP1 + (k0), &Bs[b][wv*1024+512]);         \
  }while(0)

  GSTAGE(0,0);
  asm volatile("s_waitcnt vmcnt(0)" ::: "memory");
  __syncthreads();

  int rrow=l&15, ck=l>>4;
  for (int k0=0;k0<K;k0+=32){
    int cb=(k0>>5)&1;
    if (k0+32<K) GSTAGE(cb^1, k0+32);
    s16x8 af[2], bf[4];
    #pragma unroll
    for (int mt=0;mt<2;mt++){
      int ra = wm*32+mt*16+rrow;
      af[mt]=*(const s16x8*)(&As[cb][ra*32 + ((ck ^ ((ra>>1)&3))<<3)]);
    }
    #pragma unroll
    for (int nt=0;nt<4;nt++){
      int rb = wn*64+nt*16+rrow;
      bf[nt]=*(const s16x8*)(&Bs[cb][rb*32 + ((ck ^ ((rb>>1)&3))<<3)]);
    }
    #pragma unroll
    for (int mt=0;mt<2;mt++)
      #pragma unroll
      for (int nt=0;nt<4;nt++)
        acc[mt][nt]=__builtin_amdgcn_mfma_f32_16x16x32_bf16(af[mt],bf[nt],acc[mt][nt],0,0,0);
    __syncthreads();
  }
#undef GSTAGE
  // epilogue
  #pragma unroll
  for (int mt=0;mt<2;mt++){
    #pragma unroll
    for (int nt=0;nt<4;nt++){
      int nglob = col0 + wn*64 + nt*16 + (l&15);
      if (nglob >= Nlim) continue;
      #pragma unroll
      for (int rg=0;rg<4;rg++){
        int mrow = m0 + wm*32 + mt*16 + ((l>>4)<<2) + rg;
        float val = acc[mt][nt][rg];
        if (outMode==0){
          outF[(size_t)mrow*ldc + nglob] = val;
        } else if (outMode==1){          // r bf16 -> SEQ slot 0
          int b=mrow>>10, t=mrow&1023, h=nglob>>6, i=nglob&63;
          char* cbase = SEQc + (size_t)((b*16+h)*64 + (t>>4))*24576 + (size_t)(t&15)*896;
          *(u16*)(cbase + i*2) = f2bf(val);
        } else if (outMode==2){          // decay f32 -> SEQ slot 5
          float w = bias[nglob] + val;
          float d = expf(-expf(w));
          int b=mrow>>10, t=mrow&1023, h=nglob>>6, i=nglob&63;
          char* cbase = SEQc + (size_t)((b*16+h)*64 + (t>>4))*24576 + (size_t)(t&15)*896;
          *(float*)(cbase + 640 + i*4) = d;
        } else if (outMode==3){          // sigmoid(bias+acc)
          float s = 1.0f/(1.0f+__expf(-(bias[nglob]+val)));
          outF[(size_t)mrow*ldc + nglob] = s;
        } else {                          // fused stage-1 activation -> UB bf16
          float a = (nglob<64) ? tanhf(val)
                  : (nglob<160) ? val
                  : 1.0f/(1.0f+__expf(-val));
          UBp[(size_t)mrow*384 + nglob] = f2bf(a);
        }
      }
    }
  }
}

// ---------------- prep2: build SEQ slots k,v,a,b (bf16) + dp + VEPI ----------------
__global__ __launch_bounds__(256) void prep2_kernel(char* ws, const float* vfirst,
  const float* kk_s, const float* ka_s, const float* rkw)
{
  const float* KQF=(const float*)(ws+OFF_KQF);
  const float* VQF=(const float*)(ws+OFF_VQF);
  const float* ICLR=(const float*)(ws+OFF_S2A);
  const float* VMIX=(const float*)(ws+OFF_S2V);
  u16* VEPI=(u16*)(ws+OFF_VEPI);
  float* DPp=(float*)(ws+OFF_DP);
  int m=blockIdx.x, b=m>>10, t=m&1023;
  int tid=threadIdx.x, c0=tid*4, h=c0>>6, i0=c0&63, hk=h>>1;
  f32x4 kq=*(const f32x4*)(KQF+(size_t)m*512+hk*64+i0);
  f32x4 vq=*(const f32x4*)(VQF+(size_t)m*512+hk*64+i0);
  f32x4 ic=*(const f32x4*)(ICLR+(size_t)m*1024+c0);
  f32x4 vm=*(const f32x4*)(VMIX+(size_t)m*1024+c0);
  f32x4 vf=*(const f32x4*)(vfirst+(size_t)m*1024+c0);
  f32x4 kkc=*(const f32x4*)(kk_s+c0);
  f32x4 kac=*(const f32x4*)(ka_s+c0);
  f32x4 kk=kq*kkc;
  float ssq=kk[0]*kk[0]+kk[1]*kk[1]+kk[2]*kk[2]+kk[3]*kk[3];
  #pragma unroll
  for (int mk=1;mk<16;mk<<=1) ssq += __shfl_xor(ssq,mk);
  float scale = 1.0f / fmaxf(sqrtf(ssq), 1e-12f);
  int bh=b*16+h;
  char* cb = ws + OFF_SEQ + (size_t)(bh*64+(t>>4))*24576 + (size_t)(t&15)*896;
  u16x4 rv = *(const u16x4*)(cb + (size_t)i0*2);
  f32x4 rkv = *(const f32x4*)(rkw + h*64 + i0);
  f32x4 kf,vv,av,bv;
  float dpp=0.f;
  #pragma unroll
  for (int j=0;j<4;j++){
    float icc = 1.0f + (ic[j]-1.0f)*kac[j];
    float kkn = kk[j]*scale;
    kf[j]=kq[j]*icc;
    vv[j]=vq[j] + (vf[j]-vq[j])*vm[j];
    av[j]=-kkn;
    bv[j]=kkn*icc;
    dpp += bf2f(rv[j])*kf[j]*rkv[j];
  }
  #pragma unroll
  for (int mk=1;mk<16;mk<<=1) dpp += __shfl_xor(dpp,mk);
  if ((tid&15)==0) DPp[(size_t)bh*1024 + t] = dpp;
  i32x2 o;
  o[0]=pk2(kf[0],kf[1]); o[1]=pk2(kf[2],kf[3]);
  *(i32x2*)(cb + 128 + (size_t)i0*2) = o;
  o[0]=pk2(vv[0],vv[1]); o[1]=pk2(vv[2],vv[3]);
  *(i32x2*)(cb + 256 + (size_t)i0*2) = o;
  *(i32x2*)(VEPI + ((size_t)bh*1024+t)*64 + i0) = o;
  o[0]=pk2(av[0],av[1]); o[1]=pk2(av[2],av[3]);
  *(i32x2*)(cb + 384 + (size_t)i0*2) = o;
  o[0]=pk2(bv[0],bv[1]); o[1]=pk2(bv[2],bv[3]);
  *(i32x2*)(cb + 512 + (size_t)i0*2) = o;
}

#define MFMA32(a,b,c) __builtin_amdgcn_mfma_f32_16x16x32_bf16(a,b,c,0,0,0)

// ---------------- precompute: per-chunk S-independent record (2048-way parallel) ------
__global__ __launch_bounds__(64) void pre_kernel(char* ws){
  int bid=blockIdx.x;
  int l=threadIdx.x, c16=l&15, g=l>>4;
  char* chunk = ws + OFF_SEQ + (size_t)bid*24576;
  char* rec = chunk;

  __shared__ __align__(16) char SH[31776];
  u16* AT =(u16*)(SH+14336);
  u16* RT =(u16*)(SH+16640);
  u16* BT =(u16*)(SH+18944);
  u16* KT =(u16*)(SH+21248);
  u16* vbb=(u16*)(SH+23552);
  u16* BKL=(u16*)(SH+26656);
  // overlay region (valid after column pass)
  float* WN  =(float*)(SH+0);
  u16* WY =(u16*)(SH+1088);
  u16* WB =(u16*)(SH+1888);
  u16* WK =(u16*)(SH+2688);
  u16* pbb=(u16*)(SH+3488);
  u16* zbb=(u16*)(SH+6592);
  float* rhsb=(float*)(SH+9696);
  float* gtmp=(float*)(SH+9696);   // overlays rhsb (disjoint lifetime)
  const s16x8 zero8 = {0,0,0,0,0,0,0,0};
  const f32x4 zf4 = {0.f,0.f,0.f,0.f};

  // ---- stage chunk payload (14336B, linear) ----
  #pragma unroll
  for (int q=0;q<14;q++)
    gload_lds16((const float*)(chunk + (size_t)q*1024) + l*4, (float*)(SH + q*1024));
  asm volatile("s_waitcnt vmcnt(0)" ::: "memory");
  __builtin_amdgcn_sched_barrier(0);

  // ---- column pass: lane = channel l ----
  float ptv[16]; float pp=1.f;
  #pragma unroll
  for (int t=0;t<16;t++){ pp *= *(const float*)(SH + t*896 + 640 + l*4); ptv[t]=pp; }
  float pL = ptv[15];
  *(float*)(rec + 10240 + (size_t)l*4) = pL;
  float rpL = __builtin_amdgcn_rcpf(pL);
  float bs[16], ks[16];
  u16 vcol[16];
  #pragma unroll
  for (int t=0;t<16;t++){
    float sc = pL * __builtin_amdgcn_rcpf(ptv[t]);
    bs[t] = bf2f(*(const u16*)(SH + t*896 + 512 + l*2)) * sc;
    ks[t] = bf2f(*(const u16*)(SH + t*896 + 128 + l*2)) * sc;
    vcol[t] = *(const u16*)(SH + t*896 + 256 + l*2);
  }
  {
    i32x4 o;
    o[0]=(int)((unsigned)vcol[0]|((unsigned)vcol[1]<<16));
    o[1]=(int)((unsigned)vcol[2]|((unsigned)vcol[3]<<16));
    o[2]=(int)((unsigned)vcol[4]|((unsigned)vcol[5]<<16));
    o[3]=(int)((unsigned)vcol[6]|((unsigned)vcol[7]<<16));
    *(i32x4*)(&vbb[l*24]) = o;
    o[0]=(int)((unsigned)vcol[8]|((unsigned)vcol[9]<<16));
    o[1]=(int)((unsigned)vcol[10]|((unsigned)vcol[11]<<16));
    o[2]=(int)((unsigned)vcol[12]|((unsigned)vcol[13]<<16));
    o[3]=(int)((unsigned)vcol[14]|((unsigned)vcol[15]<<16));
    *(i32x4*)(&vbb[l*24+8]) = o;
    o[0]=pk2(bs[0],bs[1]); o[1]=pk2(bs[2],bs[3]); o[2]=pk2(bs[4],bs[5]); o[3]=pk2(bs[6],bs[7]);
    *(i32x4*)(&BKL[l*40]) = o;
    o[0]=pk2(bs[8],bs[9]); o[1]=pk2(bs[10],bs[11]); o[2]=pk2(bs[12],bs[13]); o[3]=pk2(bs[14],bs[15]);
    *(i32x4*)(&BKL[l*40+8]) = o;
    o[0]=pk2(ks[0],ks[1]); o[1]=pk2(ks[2],ks[3]); o[2]=pk2(ks[4],ks[5]); o[3]=pk2(ks[6],ks[7]);
    *(i32x4*)(&BKL[l*40+16]) = o;
    o[0]=pk2(ks[8],ks[9]); o[1]=pk2(ks[10],ks[11]); o[2]=pk2(ks[12],ks[13]); o[3]=pk2(ks[14],ks[15]);
    *(i32x4*)(&BKL[l*40+24]) = o;
  }
  #pragma unroll
  for (int t=0;t<16;t++){
    float at = bf2f(*(const u16*)(SH + t*896 + 384 + l*2));
    float rt = bf2f(*(const u16*)(SH + t*896 +   0 + l*2));
    float pprev = (t==0) ? 1.f : ptv[t-1];
    AT[t*72+l] = f2bf(pprev*at);
    RT[t*72+l] = f2bf(ptv[t]*rt);
    BT[t*72+l] = f2bf(bs[t]*rpL);
    KT[t*72+l] = f2bf(ks[t]*rpL);
  }
  asm volatile("s_waitcnt lgkmcnt(0)" ::: "memory");
  __builtin_amdgcn_sched_barrier(0);

  // ---- W-block: N, Yhat, Tb, Tk ----
  {
    s16x8 afA[2], afR[2], bfB[2], bfK[2];
    #pragma unroll
    for (int Kt=0;Kt<2;Kt++){
      afA[Kt]=*(const s16x8*)(&AT[c16*72 + 32*Kt + 8*g]);
      afR[Kt]=*(const s16x8*)(&RT[c16*72 + 32*Kt + 8*g]);
      bfB[Kt]=*(const s16x8*)(&BT[c16*72 + 32*Kt + 8*g]);
      bfK[Kt]=*(const s16x8*)(&KT[c16*72 + 32*Kt + 8*g]);
    }
    f32x4 dNN=zf4, dNY=zf4, dBB=zf4, dBK=zf4;
    #pragma unroll
    for (int Kt=0;Kt<2;Kt++){
      dNN=MFMA32(afA[Kt],bfB[Kt],dNN);
      dNY=MFMA32(afA[Kt],bfK[Kt],dNY);
      dBB=MFMA32(afR[Kt],bfB[Kt],dBB);
      dBK=MFMA32(afR[Kt],bfK[Kt],dBK);
    }
    #pragma unroll
    for (int e=0;e<4;e++){
      int tR=4*g+e, sC=c16;
      WN[tR*17+sC] = dNN[e];
      WY[tR*24+sC] = (sC<tR)? f2bf(dNY[e]) : (u16)0;
      WB[tR*24+sC] = (sC<=tR)? f2bf(dBB[e]) : (u16)0;
      WK[tR*24+sC] = (sC<=tR)? f2bf(dBK[e]) : (u16)0;
    }
  }

  // ---- YhatV -> rhsb ----
  s16x8 vf[4];
  #pragma unroll
  for (int J=0;J<4;J++){
    vf[J]=zero8;
    if (g<2) vf[J]=*(const s16x8*)(&vbb[(16*J+c16)*24 + 8*g]);
  }
  {
    s16x8 wyf=zero8;
    if (g<2) wyf=*(const s16x8*)(&WY[c16*24 + 8*g]);
    f32x4 dR[4];
    #pragma unroll
    for (int J=0;J<4;J++){
      dR[J]=zf4;
      dR[J]=MFMA32(wyf,vf[J],dR[J]);
      #pragma unroll
      for (int e=0;e<4;e++)
        rhsb[(4*g+e)*68 + 16*J + c16] = dR[J][e];
    }
  }

  // ---- P-solve: (I-N)P = Atil, lane = column j=l ----
  {
    float pv[16];
    #pragma unroll
    for (int t=0;t<16;t++) pv[t]=bf2f(AT[t*72+l]);
    #pragma unroll
    for (int t=1;t<16;t++)
      #pragma unroll
      for (int s=0;s<16;s++){
        if (s<t) pv[t] += WN[t*17+s]*pv[s];
      }
    i32x4 o;
    o[0]=pk2(pv[0],pv[1]); o[1]=pk2(pv[2],pv[3]); o[2]=pk2(pv[4],pv[5]); o[3]=pk2(pv[6],pv[7]);
    *(i32x4*)(&pbb[l*24]) = o;
    o[0]=pk2(pv[8],pv[9]); o[1]=pk2(pv[10],pv[11]); o[2]=pk2(pv[12],pv[13]); o[3]=pk2(pv[14],pv[15]);
    *(i32x4*)(&pbb[l*24+8]) = o;
  }

  // ---- z-solve: (I-N)zloc = YhatV, lane = column i=l ----
  {
    float zz[16];
    #pragma unroll
    for (int t=0;t<16;t++) zz[t]=rhsb[t*68+l];
    #pragma unroll
    for (int t=1;t<16;t++)
      #pragma unroll
      for (int s=0;s<16;s++){
        if (s<t) zz[t] += WN[t*17+s]*zz[s];
      }
    i32x4 o;
    o[0]=pk2(zz[0],zz[1]); o[1]=pk2(zz[2],zz[3]); o[2]=pk2(zz[4],zz[5]); o[3]=pk2(zz[6],zz[7]);
    *(i32x4*)(&zbb[l*24]) = o;
    o[0]=pk2(zz[8],zz[9]); o[1]=pk2(zz[10],zz[11]); o[2]=pk2(zz[12],zz[13]); o[3]=pk2(zz[14],zz[15]);
    *(i32x4*)(&zbb[l*24+8]) = o;
  }
  asm volatile("s_waitcnt lgkmcnt(0)" ::: "memory");
  __builtin_amdgcn_sched_barrier(0);

  // ---- G = Rtil + Tb*P -> gtmp ; Yloc = Tb*zloc + Tk*V -> record strips ----
  {
    s16x8 wbf=zero8, wkf=zero8;
    if (g<2){
      wbf=*(const s16x8*)(&WB[c16*24 + 8*g]);
      wkf=*(const s16x8*)(&WK[c16*24 + 8*g]);
    }
    #pragma unroll
    for (int J=0;J<4;J++){
      s16x8 pfB=zero8, zfB=zero8;
      if (g<2){
        pfB=*(const s16x8*)(&pbb[(16*J+c16)*24 + 8*g]);
        zfB=*(const s16x8*)(&zbb[(16*J+c16)*24 + 8*g]);
      }
      f32x4 dG, dYl=zf4;
      #pragma unroll
      for (int e=0;e<4;e++) dG[e]=bf2f(RT[(4*g+e)*72 + 16*J + c16]);
      dG=MFMA32(wbf,pfB,dG);
      dYl=MFMA32(wbf,zfB,dYl);
      dYl=MFMA32(wkf,vf[J],dYl);
      #pragma unroll
      for (int e=0;e<4;e++) gtmp[(4*g+e)*68 + 16*J + c16]=dG[e];
      i32x2 o2; o2[0]=pk2(dYl[0],dYl[1]); o2[1]=pk2(dYl[2],dYl[3]);
      *(i32x2*)(rec + 10496 + (size_t)J*2560 + 2048 + (size_t)l*8) = o2;
    }
  }

  // ---- Q = P^T [Bbar;Kbar] tiles -> record Q A-frags; c = [Bbar;Kbar]^T [z;V] ----
  {
    s16x8 bk[4], pfr[4], bzv[4];
    #pragma unroll
    for (int nt=0;nt<4;nt++) bk[nt]=*(const s16x8*)(&BKL[(16*nt+c16)*40 + 8*g]);
    #pragma unroll
    for (int mt=0;mt<4;mt++)
      pfr[mt]= (g<2) ? *(const s16x8*)(&pbb[(16*mt+c16)*24 + 8*g]) : zero8;
    #pragma unroll
    for (int it=0;it<4;it++)
      bzv[it]= (g<2) ? *(const s16x8*)(&zbb[(16*it+c16)*24 + 8*g])
                     : *(const s16x8*)(&vbb[(16*it+c16)*24 + 8*(g-2)]);
    #pragma unroll
    for (int mt=0;mt<4;mt++){
      #pragma unroll
      for (int nt=0;nt<4;nt++){
        f32x4 dQ = MFMA32(pfr[mt], bk[nt], zf4);
        int kk = mt>>1, gq = ((mt&1)<<1) | (g>>1), jo = g&1;
        i32x2 o2; o2[0]=pk2(dQ[0],dQ[1]); o2[1]=pk2(dQ[2],dQ[3]);
        *(i32x2*)(rec + ((size_t)(kk*4+nt)*64 + (size_t)(c16 + 16*gq))*16 + 8*jo) = o2;
      }
    }
    #pragma unroll
    for (int jtp=0;jtp<4;jtp++){
      #pragma unroll
      for (int it=0;it<4;it++){
        f32x4 dc = MFMA32(bk[jtp], bzv[it], zf4);
        i32x2 o2; o2[0]=pk2(dc[0],dc[1]); o2[1]=pk2(dc[2],dc[3]);
        *(i32x2*)(rec + 10496 + (size_t)it*2560 + ((size_t)jtp*64 + l)*8) = o2;
      }
    }
  }

  // ---- G A-frags -> record ----
  #pragma unroll
  for (int kk=0;kk<2;kk++){
    f32x4 b0 = *(const f32x4*)(&gtmp[c16*68 + 32*kk + 8*g]);
    f32x4 b1 = *(const f32x4*)(&gtmp[c16*68 + 32*kk + 8*g + 4]);
    i32x4 o;
    o[0]=pk2(b0[0],b0[1]); o[1]=pk2(b0[2],b0[3]); o[2]=pk2(b1[0],b1[1]); o[3]=pk2(b1[2],b1[3]);
    *(i32x4*)(rec + 8192 + (size_t)(kk*64+l)*16) = o;
  }
}

// ---------------- serial scan: register-direct loads, 4 waves/block, depth-3 prefetch ----
// Separate __restrict__ args break the record-load / y-store alias chain so the
// compiler can hoist prefetch loads across stores.
__global__ __launch_bounds__(256, 1) void scan2_kernel(
    const char* __restrict__ recb, float* __restrict__ YB,
    const float* __restrict__ S0, float* __restrict__ dout){
  int bh=blockIdx.x;
  int tid=threadIdx.x, w=tid>>6, l=tid&63, c16=l&15, g=l>>4;

  __shared__ __align__(16) u16 ST[4][16*88];
  u16* STw = &ST[w][0];

  f32x4 Sreg[4];
  #pragma unroll
  for (int jt=0;jt<4;jt++)
    Sreg[jt] = *(const f32x4*)(S0 + (size_t)bh*4096 + (size_t)(16*w+c16)*64 + 16*jt + 4*g);
  #pragma unroll
  for (int jt=0;jt<4;jt++){
    i32x2 p; p[0]=pk2(Sreg[jt][0],Sreg[jt][1]); p[1]=pk2(Sreg[jt][2],Sreg[jt][3]);
    *(i32x2*)(&STw[c16*88 + 16*jt + 4*g]) = p;
  }

  const char* rb = recb + (size_t)(bh*64)*24576;
  float* yb0 = YB + (size_t)bh*65536;

#define DECLR(S) s16x8 qf##S[8]; s16x8 gf##S[2]; f32x4 pl##S[4]; i32x2 cf##S[4]; i32x2 yl##S;
#define LOADR(S, nc) do{ \
    const char* rp_ = rb + (size_t)(nc)*24576; \
    _Pragma("unroll") \
    for (int q_=0;q_<8;q_++) qf##S[q_] = *(const s16x8*)(rp_ + (size_t)q_*1024 + l*16); \
    gf##S[0] = *(const s16x8*)(rp_ + 8192 + (size_t)l*16); \
    gf##S[1] = *(const s16x8*)(rp_ + 9216 + (size_t)l*16); \
    _Pragma("unroll") \
    for (int jt_=0;jt_<4;jt_++) pl##S[jt_] = *(const f32x4*)(rp_ + 10240 + (size_t)(16*jt_+4*g)*4); \
    _Pragma("unroll") \
    for (int jt_=0;jt_<4;jt_++) cf##S[jt_] = *(const i32x2*)(rp_ + 10496 + (size_t)w*2560 + (size_t)(jt_*64+l)*8); \
    yl##S = *(const i32x2*)(rp_ + 10496 + (size_t)w*2560 + 2048 + (size_t)l*8); \
  }while(0)
#define STEP(S, ch) do{ \
    s16x8 sB0=*(const s16x8*)(&STw[c16*88 + 8*g]); \
    s16x8 sB1=*(const s16x8*)(&STw[c16*88 + 32 + 8*g]); \
    /* critical S' update first (feeds the recurrence) */ \
    _Pragma("unroll") \
    for (int jt_=0;jt_<4;jt_++){ \
      f32x4 acc = cvt4(cf##S[jt_]); \
      acc = MFMA32(qf##S[jt_], sB0, acc); \
      acc = MFMA32(qf##S[4+jt_], sB1, acc); \
      _Pragma("unroll") \
      for (int e_=0;e_<4;e_++) acc[e_] = fmaf(pl##S[jt_][e_], Sreg[jt_][e_], acc[e_]); \
      Sreg[jt_]=acc; \
    } \
    _Pragma("unroll") \
    for (int jt_=0;jt_<4;jt_++){ \
      i32x2 p_; p_[0]=cvtpk(Sreg[jt_][0],Sreg[jt_][1]); p_[1]=cvtpk(Sreg[jt_][2],Sreg[jt_][3]); \
      *(i32x2*)(&STw[c16*88 + 16*jt_ + 4*g]) = p_; \
    } \
    /* y output (off the critical chain) */ \
    f32x4 dy=cvt4(yl##S); \
    dy=MFMA32(gf##S[0],sB0,dy); dy=MFMA32(gf##S[1],sB1,dy); \
    { float* yb_ = yb0 + (size_t)(ch)*1024; \
      _Pragma("unroll") \
      for (int e_=0;e_<4;e_++) yb_[(size_t)(4*g+e_)*64 + 16*w + c16] = dy[e_]; } \
  }while(0)

  DECLR(A); DECLR(B); DECLR(C);
  LOADR(A, 0);
  LOADR(B, 1);
  LOADR(C, 2);

  // 64 chunks = 21 iterations x 3 + 1 epilogue
  #pragma unroll 1
  for (int ch=0; ch<63; ch+=3){
    STEP(A, ch);
    { int nc = ch+3; if (nc>63) nc=63; LOADR(A, nc); }
    STEP(B, ch+1);
    { int nc = ch+4; if (nc>63) nc=63; LOADR(B, nc); }
    STEP(C, ch+2);
    { int nc = ch+5; if (nc>63) nc=63; LOADR(C, nc); }
  }
  STEP(A, 63);
#undef DECLR
#undef LOADR
#undef STEP

  #pragma unroll
  for (int jt=0;jt<4;jt++)
    *(f32x4*)(dout + 2097152 + (size_t)bh*4096 + (size_t)(16*w+c16)*64 + 16*jt + 4*g) = Sreg[jt];
}

// ---------------- epilogue: groupnorm + bonus + gate -> bf16 ----------------
__global__ __launch_bounds__(256) void epi_kernel(char* ws, const float* lnw, const float* lnb)
{
  const float* YB=(const float*)(ws+OFF_YBUF);
  const u16* VEPI=(const u16*)(ws+OFF_VEPI);
  const float* DPp=(const float*)(ws+OFF_DP);
  const float* GB=(const float*)(ws+OFF_GBUF);
  u16* XGB=(u16*)(ws+OFF_XGB);
  int m=blockIdx.x, b=m>>10, t=m&1023;
  int tid=threadIdx.x, c0=tid*4, h=c0>>6, i0=c0&63;
  f32x4 y=*(const f32x4*)(YB + ((size_t)(b*16+h)*1024+t)*64 + i0);
  float s = y[0]+y[1]+y[2]+y[3];
  float ss= y[0]*y[0]+y[1]*y[1]+y[2]*y[2]+y[3]*y[3];
  #pragma unroll
  for (int mk=1;mk<16;mk<<=1){ s+=__shfl_xor(s,mk); ss+=__shfl_xor(ss,mk); }
  float mu=s*(1.0f/64.0f), var=ss*(1.0f/64.0f)-mu*mu;
  float inv=rsqrtf(var + 6.4e-4f);
  u16x4 v16=*(const u16x4*)(VEPI + ((size_t)(b*16+h)*1024+t)*64 + i0);
  float dp = DPp[(size_t)(b*16+h)*1024 + t];
  f32x4 gg=*(const f32x4*)(GB+(size_t)m*1024+c0);
  u16x4 outv;
  #pragma unroll
  for (int j=0;j<4;j++){
    float xn = (y[j]-mu)*inv*lnw[c0+j] + lnb[c0+j] + dp*bf2f(v16[j]);
    outv[j]=f2bf(xn*gg[j]);
  }
  *(u16x4*)(XGB+(size_t)m*1024+c0)=outv;
}

extern "C" void kernel_launch(void* const* d_in, const int* in_sizes, int n_in,
                              void* d_out, int out_size, void* d_ws, size_t ws_size,
                              hipStream_t stream) {
  const float* x      =(const float*)d_in[0];
  const float* S0     =(const float*)d_in[1];
  const float* vfirst =(const float*)d_in[2];
  const float* w0     =(const float*)d_in[3];
  const float* w1     =(const float*)d_in[4];
  const float* w2     =(const float*)d_in[5];
  const float* a0     =(const float*)d_in[6];
  const float* a1     =(const float*)d_in[7];
  const float* a2     =(const float*)d_in[8];
  const float* v0     =(const float*)d_in[9];
  const float* v1     =(const float*)d_in[10];
  const float* v2     =(const float*)d_in[11];
  const float* g1     =(const float*)d_in[12];
  const float* g2     =(const float*)d_in[13];
  const float* k_k    =(const float*)d_in[14];
  const float* k_a    =(const float*)d_in[15];
  const float* r_k    =(const float*)d_in[16];
  const float* Wq     =(const float*)d_in[17];
  const float* Wk     =(const float*)d_in[18];
  const float* Wv     =(const float*)d_in[19];
  const float* Wo     =(const float*)d_in[20];
  const float* ln_w   =(const float*)d_in[21];
  const float* ln_b   =(const float*)d_in[22];
  char* ws=(char*)d_ws;
  float* dout=(float*)d_out;

  prep_kernel<<<2048,256,0,stream>>>(ws,x,vfirst,w1,w2,a1,a2,v1,v2,g1,g2,Wq,Wk,Wv,Wo,dout);
  gemm_kernel<<<dim3(32,19),256,0,stream>>>(0,ws,w0,a0,v0,dout);
  gemm_kernel<<<dim3(32,32),256,0,stream>>>(1,ws,w0,a0,v0,dout);
  prep2_kernel<<<2048,256,0,stream>>>(ws,vfirst,k_k,k_a,r_k);
  pre_kernel<<<2048,64,0,stream>>>(ws);
  scan2_kernel<<<32,256,0,stream>>>(ws+OFF_SEQ, (float*)(ws+OFF_YBUF), S0, dout);
  epi_kernel<<<2048,256,0,stream>>>(ws,ln_w,ln_b);
  gemm_kernel<<<dim3(32,8),256,0,stream>>>(2,ws,w0,a0,v0,dout);
}

// Round 19
// 158.822 us; speedup vs baseline: 1.0113x; 1.0113x over previous
//
#include <hip/hip_runtime.h>

typedef unsigned short u16;
typedef __attribute__((ext_vector_type(8))) short s16x8;
typedef __attribute__((ext_vector_type(4))) float f32x4;
typedef __attribute__((ext_vector_type(4))) int   i32x4;
typedef __attribute__((ext_vector_type(2))) int   i32x2;
typedef __attribute__((ext_vector_type(4))) unsigned short u16x4;

// ---------------- workspace layout (bytes) ----------------
constexpr size_t OFF_XB   = 0;                     // bf16 x [2048][1024]; later VEPI
constexpr size_t OFF_WQB  = OFF_XB   + 4194304;    // bf16 Wq         [1024][1024]
constexpr size_t OFF_WKB  = OFF_WQB  + 2097152;    // bf16 Wk         [512][1024]
constexpr size_t OFF_WVB  = OFF_WKB  + 1048576;    // bf16 Wv         [512][1024]
constexpr size_t OFF_WOB  = OFF_WVB  + 1048576;    // bf16 Wo         [1024][1024]
constexpr size_t OFF_W1T  = OFF_WOB  + 2097152;    // bf16 W1T [384][1024]; later DP
constexpr size_t OFF_W2T  = OFF_W1T  + 786432;     // bf16 w2T        [1024][64]
constexpr size_t OFF_A2T  = OFF_W2T  + 131072;     // bf16 a2T        [1024][64]
constexpr size_t OFF_V2T  = OFF_A2T  + 131072;     // bf16 v2T        [1024][32]
constexpr size_t OFF_G2T  = OFF_V2T  + 65536;      // bf16 g2T        [1024][160]
constexpr size_t OFF_KQF  = OFF_G2T  + 327680;     // f32 k-proj      [2048][512]
constexpr size_t OFF_VQF  = OFF_KQF  + 4194304;    // f32 v-proj      [2048][512]
constexpr size_t OFF_URAW = OFF_VQF  + 4194304;    // (dead)
constexpr size_t OFF_UB   = OFF_URAW + 2621440;    // bf16 stage1 act [2048][384]
constexpr size_t OFF_S2A  = OFF_UB   + 1572864;    // f32 iclr        [2048][1024]
constexpr size_t OFF_S2V  = OFF_S2A  + 8388608;    // f32 vmix        [2048][1024]
constexpr size_t OFF_GBUF = OFF_S2V  + 8388608;    // f32 gate        [2048][1024]
constexpr size_t OFF_SEQ  = OFF_GBUF + 8388608;    // chunks [2048][24576B]; later records
constexpr size_t OFF_YBUF = OFF_SEQ  + 50331648;   // f32 y   [2][16][1024][64]
constexpr size_t OFF_XGB  = OFF_YBUF + 8388608;    // bf16 xn*g       [2048][1024]

// SEQ chunk payload (first 14336B of each 24576B slot), per t-row stride 896:
//  +0 r bf16[64] | +128 k | +256 v | +384 a | +512 b | +640 decay f32[64]
// record overlay (pre overwrites its OWN chunk): 0 Q(8192) | 8192 G(2048) |
//  10240 pL f32[64] | 10496 + w*2560 { c[jt4][lane]x8B (2048) | Yloc (512) }
constexpr size_t OFF_VEPI = OFF_XB;                // bf16 v rows (XB dead after gemm0)
constexpr size_t OFF_DP   = OFF_W1T;               // f32 dp (W1T dead after gemm0)

__device__ __forceinline__ u16 f2bf(float f){
  unsigned int u = __builtin_bit_cast(unsigned int, f);
  u = u + 0x7fffu + ((u >> 16) & 1u);
  return (u16)(u >> 16);
}
__device__ __forceinline__ int pk2(float a, float b){
  return (int)((unsigned)f2bf(a) | ((unsigned)f2bf(b) << 16));
}
__device__ __forceinline__ int cvtpk(float a, float b){
  int r;
  asm("v_cvt_pk_bf16_f32 %0, %1, %2" : "=v"(r) : "v"(a), "v"(b));
  return r;
}
__device__ __forceinline__ float bf2f(u16 h){
  return __builtin_bit_cast(float, ((unsigned)h) << 16);
}
__device__ __forceinline__ f32x4 cvt4(i32x2 v){
  unsigned a=(unsigned)v[0], b=(unsigned)v[1];
  f32x4 r;
  r[0]=__builtin_bit_cast(float, a<<16);
  r[1]=__builtin_bit_cast(float, a&0xffff0000u);
  r[2]=__builtin_bit_cast(float, b<<16);
  r[3]=__builtin_bit_cast(float, b&0xffff0000u);
  return r;
}

__device__ __forceinline__ void gload_lds16(const float* g, float* l){
  __builtin_amdgcn_global_load_lds((const __attribute__((address_space(1))) void*)g,
                                   (__attribute__((address_space(3))) void*)l, 16, 0, 0);
}
__device__ __forceinline__ void gload_lds16u(const u16* g, u16* l){
  __builtin_amdgcn_global_load_lds((const __attribute__((address_space(1))) void*)g,
                                   (__attribute__((address_space(3))) void*)l, 16, 0, 0);
}

// ---------------- prep: vectorized convert + transposes + v_first passthrough ----------------
constexpr size_t N_XB=2097152, N_WQ=1048576, N_WK=524288, N_WV=524288, N_WO=1048576,
  N_W1T=393216, N_W2T=65536, N_A2T=65536, N_V2T=32768, N_G2T=163840, N_VF=2097152;
constexpr size_t NV_BULK = (N_XB+N_WQ+N_WK+N_WV+N_WO)/4;   // vectorized bf16 copies
constexpr size_t NV_VF   = N_VF/4;                          // vectorized f32 copy
constexpr size_t N_SCAL  = N_W1T+N_W2T+N_A2T+N_V2T+N_G2T;   // scalar transposes
constexpr size_t PREP_TOT = NV_BULK + NV_VF + N_SCAL;

__global__ __launch_bounds__(256) void prep_kernel(char* ws, const float* x, const float* vfirst,
  const float* w1, const float* w2, const float* a1, const float* a2,
  const float* v1, const float* v2, const float* g1, const float* g2,
  const float* Wq, const float* Wk, const float* Wv, const float* Wo, float* dout)
{
  u16* XB=(u16*)(ws+OFF_XB); u16* WQB=(u16*)(ws+OFF_WQB); u16* WKB=(u16*)(ws+OFF_WKB);
  u16* WVB=(u16*)(ws+OFF_WVB); u16* WOB=(u16*)(ws+OFF_WOB); u16* W1T=(u16*)(ws+OFF_W1T);
  u16* W2T=(u16*)(ws+OFF_W2T); u16* A2T=(u16*)(ws+OFF_A2T); u16* V2T=(u16*)(ws+OFF_V2T);
  u16* G2T=(u16*)(ws+OFF_G2T);
  for (size_t idx=(size_t)blockIdx.x*256+threadIdx.x; idx<PREP_TOT; idx+=(size_t)gridDim.x*256){
    size_t r = idx;
    if (r < NV_BULK){
      size_t e = r*4;
      const float* src; u16* dst;
      if (e < N_XB){ src=x+e; dst=XB+e; }
      else { e-=N_XB;
        if (e < N_WQ){ src=Wq+e; dst=WQB+e; }
        else { e-=N_WQ;
          if (e < N_WK){ src=Wk+e; dst=WKB+e; }
          else { e-=N_WK;
            if (e < N_WV){ src=Wv+e; dst=WVB+e; }
            else { e-=N_WV; src=Wo+e; dst=WOB+e; }
          }
        }
      }
      f32x4 v=*(const f32x4*)src;
      u16x4 o; o[0]=f2bf(v[0]); o[1]=f2bf(v[1]); o[2]=f2bf(v[2]); o[3]=f2bf(v[3]);
      *(u16x4*)dst=o;
      continue;
    }
    r -= NV_BULK;
    if (r < NV_VF){
      size_t e=r*4;
      *(f32x4*)(dout + 2228224 + e) = *(const f32x4*)(vfirst + e);
      continue;
    }
    r -= NV_VF;
    if (r < N_W1T){
      int n=(int)(r>>10), k=(int)(r&1023); float v=0.f;
      if (n<64) v=w1[(size_t)k*64+n];
      else if (n<128) v=a1[(size_t)k*64+(n-64)];
      else if (n<160) v=v1[(size_t)k*32+(n-128)];
      else if (n<320) v=g1[(size_t)k*160+(n-160)];
      W1T[r]=f2bf(v); continue; } r-=N_W1T;
    if (r < N_W2T){ int c=(int)(r>>6), d=(int)(r&63); W2T[r]=f2bf(w2[(size_t)d*1024+c]); continue; } r-=N_W2T;
    if (r < N_A2T){ int c=(int)(r>>6), d=(int)(r&63); A2T[r]=f2bf(a2[(size_t)d*1024+c]); continue; } r-=N_A2T;
    if (r < N_V2T){ int c=(int)(r>>5), d=(int)(r&31); V2T[r]=f2bf(v2[(size_t)d*1024+c]); continue; } r-=N_V2T;
    { int c=(int)(r/160), d=(int)(r%160); G2T[r]=f2bf(g2[(size_t)d*1024+c]); }
  }
}

// ---------------- unified NT bf16 MFMA GEMM: C[m][n] = sum_k A[m][k]*B[n][k] ----------------
// 64x128 tile, 4 waves (2Mx2N), LDS 24KB; global_load_lds staging with XOR chunk swizzle.
__global__ __launch_bounds__(256) void gemm_kernel(int phase, char* ws,
  const float* w0b, const float* a0b, const float* v0b, float* dout)
{
  const u16* A; const u16* Bw;
  float* outF=nullptr; const float* bias=nullptr;
  char* SEQc=(char*)(ws+OFF_SEQ);
  u16* UBp=(u16*)(ws+OFF_UB);
  int lda=0, ldb=0, K=0, ldc=0, Nlim=1024, col0=0, outMode=0;
  int y = blockIdx.y;
  if (phase==0){
    A=(const u16*)(ws+OFF_XB); lda=1024; K=1024;
    if (y<8)      { Bw=(const u16*)(ws+OFF_WQB); ldb=1024; col0=y*128;       outMode=1; }
    else if (y<12){ Bw=(const u16*)(ws+OFF_WKB); ldb=1024; col0=(y-8)*128;   outF=(float*)(ws+OFF_KQF); ldc=512; Nlim=512; }
    else if (y<16){ Bw=(const u16*)(ws+OFF_WVB); ldb=1024; col0=(y-12)*128;  outF=(float*)(ws+OFF_VQF); ldc=512; Nlim=512; }
    else          { Bw=(const u16*)(ws+OFF_W1T); ldb=1024; col0=(y-16)*128;  outMode=4; Nlim=320; }
  } else if (phase==1){
    int seg=y>>3; col0=(y&7)*128;
    const int Ks[4]={64,64,32,160};
    const int Ao[4]={0,64,128,160};
    K=Ks[seg]; lda=384; ldb=K;
    A=(const u16*)(ws+OFF_UB) + Ao[seg];
    if (seg==0)     { Bw=(const u16*)(ws+OFF_W2T); outMode=2; bias=w0b; }
    else if (seg==1){ Bw=(const u16*)(ws+OFF_A2T); outMode=3; bias=a0b; outF=(float*)(ws+OFF_S2A); ldc=1024; }
    else if (seg==2){ Bw=(const u16*)(ws+OFF_V2T); outMode=3; bias=v0b; outF=(float*)(ws+OFF_S2V); ldc=1024; }
    else            { Bw=(const u16*)(ws+OFF_G2T); outF=(float*)(ws+OFF_GBUF); ldc=1024; }
  } else {
    A=(const u16*)(ws+OFF_XGB); lda=1024; K=1024;
    Bw=(const u16*)(ws+OFF_WOB); ldb=1024; col0=y*128; outF=dout; ldc=1024;
  }
  int m0 = blockIdx.x*64;
  __shared__ __align__(16) u16 As[2][2048];   // 64 x 32
  __shared__ __align__(16) u16 Bs[2][4096];   // 128 x 32
  int tid=threadIdx.x, l=tid&63, wv=tid>>6, wm=wv>>1, wn=wv&1;

  int cswz = (l&3) ^ ((l>>3)&3);
  int srA = wv*16 + (l>>2);
  int srB = wv*32 + (l>>2);
  const u16* aP0 = A  + (size_t)(m0+srA)*lda       + cswz*8;
  const u16* bP0 = Bw + (size_t)(col0+srB)*ldb     + cswz*8;
  const u16* bP1 = Bw + (size_t)(col0+srB+16)*ldb  + cswz*8;

  f32x4 acc[2][4];
  #pragma unroll
  for (int i=0;i<2;i++)
    #pragma unroll
    for (int j=0;j<4;j++) acc[i][j]=(f32x4){0.f,0.f,0.f,0.f};

#define GSTAGE(b,k0) do{                                   \
    gload_lds16u(aP0 + (k0), &As[b][wv*512]);              \
    gload_lds16u(bP0 + (k0), &Bs[b][wv*1024]);             \
    gload_lds16u(bP1 + (k0), &Bs[b][wv*1024+512]);         \
  }while(0)

  GSTAGE(0,0);
  asm volatile("s_waitcnt vmcnt(0)" ::: "memory");
  __syncthreads();

  int rrow=l&15, ck=l>>4;
  for (int k0=0;k0<K;k0+=32){
    int cb=(k0>>5)&1;
    if (k0+32<K) GSTAGE(cb^1, k0+32);
    s16x8 af[2], bf[4];
    #pragma unroll
    for (int mt=0;mt<2;mt++){
      int ra = wm*32+mt*16+rrow;
      af[mt]=*(const s16x8*)(&As[cb][ra*32 + ((ck ^ ((ra>>1)&3))<<3)]);
    }
    #pragma unroll
    for (int nt=0;nt<4;nt++){
      int rb = wn*64+nt*16+rrow;
      bf[nt]=*(const s16x8*)(&Bs[cb][rb*32 + ((ck ^ ((rb>>1)&3))<<3)]);
    }
    #pragma unroll
    for (int mt=0;mt<2;mt++)
      #pragma unroll
      for (int nt=0;nt<4;nt++)
        acc[mt][nt]=__builtin_amdgcn_mfma_f32_16x16x32_bf16(af[mt],bf[nt],acc[mt][nt],0,0,0);
    __syncthreads();
  }
#undef GSTAGE
  // epilogue
  #pragma unroll
  for (int mt=0;mt<2;mt++){
    #pragma unroll
    for (int nt=0;nt<4;nt++){
      int nglob = col0 + wn*64 + nt*16 + (l&15);
      if (nglob >= Nlim) continue;
      #pragma unroll
      for (int rg=0;rg<4;rg++){
        int mrow = m0 + wm*32 + mt*16 + ((l>>4)<<2) + rg;
        float val = acc[mt][nt][rg];
        if (outMode==0){
          outF[(size_t)mrow*ldc + nglob] = val;
        } else if (outMode==1){          // r bf16 -> SEQ slot 0
          int b=mrow>>10, t=mrow&1023, h=nglob>>6, i=nglob&63;
          char* cbase = SEQc + (size_t)((b*16+h)*64 + (t>>4))*24576 + (size_t)(t&15)*896;
          *(u16*)(cbase + i*2) = f2bf(val);
        } else if (outMode==2){          // decay f32 -> SEQ slot 5
          float w = bias[nglob] + val;
          float d = expf(-expf(w));
          int b=mrow>>10, t=mrow&1023, h=nglob>>6, i=nglob&63;
          char* cbase = SEQc + (size_t)((b*16+h)*64 + (t>>4))*24576 + (size_t)(t&15)*896;
          *(float*)(cbase + 640 + i*4) = d;
        } else if (outMode==3){          // sigmoid(bias+acc)
          float s = 1.0f/(1.0f+__expf(-(bias[nglob]+val)));
          outF[(size_t)mrow*ldc + nglob] = s;
        } else {                          // fused stage-1 activation -> UB bf16
          float a = (nglob<64) ? tanhf(val)
                  : (nglob<160) ? val
                  : 1.0f/(1.0f+__expf(-val));
          UBp[(size_t)mrow*384 + nglob] = f2bf(a);
        }
      }
    }
  }
}

// ---------------- prep2: build SEQ slots k,v,a,b (bf16) + dp + VEPI ----------------
__global__ __launch_bounds__(256) void prep2_kernel(char* ws, const float* vfirst,
  const float* kk_s, const float* ka_s, const float* rkw)
{
  const float* KQF=(const float*)(ws+OFF_KQF);
  const float* VQF=(const float*)(ws+OFF_VQF);
  const float* ICLR=(const float*)(ws+OFF_S2A);
  const float* VMIX=(const float*)(ws+OFF_S2V);
  u16* VEPI=(u16*)(ws+OFF_VEPI);
  float* DPp=(float*)(ws+OFF_DP);
  int m=blockIdx.x, b=m>>10, t=m&1023;
  int tid=threadIdx.x, c0=tid*4, h=c0>>6, i0=c0&63, hk=h>>1;
  f32x4 kq=*(const f32x4*)(KQF+(size_t)m*512+hk*64+i0);
  f32x4 vq=*(const f32x4*)(VQF+(size_t)m*512+hk*64+i0);
  f32x4 ic=*(const f32x4*)(ICLR+(size_t)m*1024+c0);
  f32x4 vm=*(const f32x4*)(VMIX+(size_t)m*1024+c0);
  f32x4 vf=*(const f32x4*)(vfirst+(size_t)m*1024+c0);
  f32x4 kkc=*(const f32x4*)(kk_s+c0);
  f32x4 kac=*(const f32x4*)(ka_s+c0);
  f32x4 kk=kq*kkc;
  float ssq=kk[0]*kk[0]+kk[1]*kk[1]+kk[2]*kk[2]+kk[3]*kk[3];
  #pragma unroll
  for (int mk=1;mk<16;mk<<=1) ssq += __shfl_xor(ssq,mk);
  float scale = 1.0f / fmaxf(sqrtf(ssq), 1e-12f);
  int bh=b*16+h;
  char* cb = ws + OFF_SEQ + (size_t)(bh*64+(t>>4))*24576 + (size_t)(t&15)*896;
  u16x4 rv = *(const u16x4*)(cb + (size_t)i0*2);
  f32x4 rkv = *(const f32x4*)(rkw + h*64 + i0);
  f32x4 kf,vv,av,bv;
  float dpp=0.f;
  #pragma unroll
  for (int j=0;j<4;j++){
    float icc = 1.0f + (ic[j]-1.0f)*kac[j];
    float kkn = kk[j]*scale;
    kf[j]=kq[j]*icc;
    vv[j]=vq[j] + (vf[j]-vq[j])*vm[j];
    av[j]=-kkn;
    bv[j]=kkn*icc;
    dpp += bf2f(rv[j])*kf[j]*rkv[j];
  }
  #pragma unroll
  for (int mk=1;mk<16;mk<<=1) dpp += __shfl_xor(dpp,mk);
  if ((tid&15)==0) DPp[(size_t)bh*1024 + t] = dpp;
  i32x2 o;
  o[0]=pk2(kf[0],kf[1]); o[1]=pk2(kf[2],kf[3]);
  *(i32x2*)(cb + 128 + (size_t)i0*2) = o;
  o[0]=pk2(vv[0],vv[1]); o[1]=pk2(vv[2],vv[3]);
  *(i32x2*)(cb + 256 + (size_t)i0*2) = o;
  *(i32x2*)(VEPI + ((size_t)bh*1024+t)*64 + i0) = o;
  o[0]=pk2(av[0],av[1]); o[1]=pk2(av[2],av[3]);
  *(i32x2*)(cb + 384 + (size_t)i0*2) = o;
  o[0]=pk2(bv[0],bv[1]); o[1]=pk2(bv[2],bv[3]);
  *(i32x2*)(cb + 512 + (size_t)i0*2) = o;
}

#define MFMA32(a,b,c) __builtin_amdgcn_mfma_f32_16x16x32_bf16(a,b,c,0,0,0)

// ---------------- precompute: per-chunk S-independent record (2048-way parallel) ------
__global__ __launch_bounds__(64) void pre_kernel(char* ws){
  int bid=blockIdx.x;
  int l=threadIdx.x, c16=l&15, g=l>>4;
  char* chunk = ws + OFF_SEQ + (size_t)bid*24576;
  char* rec = chunk;

  __shared__ __align__(16) char SH[31776];
  u16* AT =(u16*)(SH+14336);
  u16* RT =(u16*)(SH+16640);
  u16* BT =(u16*)(SH+18944);
  u16* KT =(u16*)(SH+21248);
  u16* vbb=(u16*)(SH+23552);
  u16* BKL=(u16*)(SH+26656);
  // overlay region (valid after column pass)
  float* WN  =(float*)(SH+0);
  u16* WY =(u16*)(SH+1088);
  u16* WB =(u16*)(SH+1888);
  u16* WK =(u16*)(SH+2688);
  u16* pbb=(u16*)(SH+3488);
  u16* zbb=(u16*)(SH+6592);
  float* rhsb=(float*)(SH+9696);
  float* gtmp=(float*)(SH+9696);   // overlays rhsb (disjoint lifetime)
  const s16x8 zero8 = {0,0,0,0,0,0,0,0};
  const f32x4 zf4 = {0.f,0.f,0.f,0.f};

  // ---- stage chunk payload (14336B, linear) ----
  #pragma unroll
  for (int q=0;q<14;q++)
    gload_lds16((const float*)(chunk + (size_t)q*1024) + l*4, (float*)(SH + q*1024));
  asm volatile("s_waitcnt vmcnt(0)" ::: "memory");
  __builtin_amdgcn_sched_barrier(0);

  // ---- column pass: lane = channel l ----
  float ptv[16]; float pp=1.f;
  #pragma unroll
  for (int t=0;t<16;t++){ pp *= *(const float*)(SH + t*896 + 640 + l*4); ptv[t]=pp; }
  float pL = ptv[15];
  *(float*)(rec + 10240 + (size_t)l*4) = pL;
  float rpL = __builtin_amdgcn_rcpf(pL);
  float bs[16], ks[16];
  u16 vcol[16];
  #pragma unroll
  for (int t=0;t<16;t++){
    float sc = pL * __builtin_amdgcn_rcpf(ptv[t]);
    bs[t] = bf2f(*(const u16*)(SH + t*896 + 512 + l*2)) * sc;
    ks[t] = bf2f(*(const u16*)(SH + t*896 + 128 + l*2)) * sc;
    vcol[t] = *(const u16*)(SH + t*896 + 256 + l*2);
  }
  {
    i32x4 o;
    o[0]=(int)((unsigned)vcol[0]|((unsigned)vcol[1]<<16));
    o[1]=(int)((unsigned)vcol[2]|((unsigned)vcol[3]<<16));
    o[2]=(int)((unsigned)vcol[4]|((unsigned)vcol[5]<<16));
    o[3]=(int)((unsigned)vcol[6]|((unsigned)vcol[7]<<16));
    *(i32x4*)(&vbb[l*24]) = o;
    o[0]=(int)((unsigned)vcol[8]|((unsigned)vcol[9]<<16));
    o[1]=(int)((unsigned)vcol[10]|((unsigned)vcol[11]<<16));
    o[2]=(int)((unsigned)vcol[12]|((unsigned)vcol[13]<<16));
    o[3]=(int)((unsigned)vcol[14]|((unsigned)vcol[15]<<16));
    *(i32x4*)(&vbb[l*24+8]) = o;
    o[0]=pk2(bs[0],bs[1]); o[1]=pk2(bs[2],bs[3]); o[2]=pk2(bs[4],bs[5]); o[3]=pk2(bs[6],bs[7]);
    *(i32x4*)(&BKL[l*40]) = o;
    o[0]=pk2(bs[8],bs[9]); o[1]=pk2(bs[10],bs[11]); o[2]=pk2(bs[12],bs[13]); o[3]=pk2(bs[14],bs[15]);
    *(i32x4*)(&BKL[l*40+8]) = o;
    o[0]=pk2(ks[0],ks[1]); o[1]=pk2(ks[2],ks[3]); o[2]=pk2(ks[4],ks[5]); o[3]=pk2(ks[6],ks[7]);
    *(i32x4*)(&BKL[l*40+16]) = o;
    o[0]=pk2(ks[8],ks[9]); o[1]=pk2(ks[10],ks[11]); o[2]=pk2(ks[12],ks[13]); o[3]=pk2(ks[14],ks[15]);
    *(i32x4*)(&BKL[l*40+24]) = o;
  }
  #pragma unroll
  for (int t=0;t<16;t++){
    float at = bf2f(*(const u16*)(SH + t*896 + 384 + l*2));
    float rt = bf2f(*(const u16*)(SH + t*896 +   0 + l*2));
    float pprev = (t==0) ? 1.f : ptv[t-1];
    AT[t*72+l] = f2bf(pprev*at);
    RT[t*72+l] = f2bf(ptv[t]*rt);
    BT[t*72+l] = f2bf(bs[t]*rpL);
    KT[t*72+l] = f2bf(ks[t]*rpL);
  }
  asm volatile("s_waitcnt lgkmcnt(0)" ::: "memory");
  __builtin_amdgcn_sched_barrier(0);

  // ---- W-block: N, Yhat, Tb, Tk ----
  {
    s16x8 afA[2], afR[2], bfB[2], bfK[2];
    #pragma unroll
    for (int Kt=0;Kt<2;Kt++){
      afA[Kt]=*(const s16x8*)(&AT[c16*72 + 32*Kt + 8*g]);
      afR[Kt]=*(const s16x8*)(&RT[c16*72 + 32*Kt + 8*g]);
      bfB[Kt]=*(const s16x8*)(&BT[c16*72 + 32*Kt + 8*g]);
      bfK[Kt]=*(const s16x8*)(&KT[c16*72 + 32*Kt + 8*g]);
    }
    f32x4 dNN=zf4, dNY=zf4, dBB=zf4, dBK=zf4;
    #pragma unroll
    for (int Kt=0;Kt<2;Kt++){
      dNN=MFMA32(afA[Kt],bfB[Kt],dNN);
      dNY=MFMA32(afA[Kt],bfK[Kt],dNY);
      dBB=MFMA32(afR[Kt],bfB[Kt],dBB);
      dBK=MFMA32(afR[Kt],bfK[Kt],dBK);
    }
    #pragma unroll
    for (int e=0;e<4;e++){
      int tR=4*g+e, sC=c16;
      WN[tR*17+sC] = dNN[e];
      WY[tR*24+sC] = (sC<tR)? f2bf(dNY[e]) : (u16)0;
      WB[tR*24+sC] = (sC<=tR)? f2bf(dBB[e]) : (u16)0;
      WK[tR*24+sC] = (sC<=tR)? f2bf(dBK[e]) : (u16)0;
    }
  }

  // ---- YhatV -> rhsb ----
  s16x8 vf[4];
  #pragma unroll
  for (int J=0;J<4;J++){
    vf[J]=zero8;
    if (g<2) vf[J]=*(const s16x8*)(&vbb[(16*J+c16)*24 + 8*g]);
  }
  {
    s16x8 wyf=zero8;
    if (g<2) wyf=*(const s16x8*)(&WY[c16*24 + 8*g]);
    f32x4 dR[4];
    #pragma unroll
    for (int J=0;J<4;J++){
      dR[J]=zf4;
      dR[J]=MFMA32(wyf,vf[J],dR[J]);
      #pragma unroll
      for (int e=0;e<4;e++)
        rhsb[(4*g+e)*68 + 16*J + c16] = dR[J][e];
    }
  }

  // ---- P-solve: (I-N)P = Atil, lane = column j=l ----
  {
    float pv[16];
    #pragma unroll
    for (int t=0;t<16;t++) pv[t]=bf2f(AT[t*72+l]);
    #pragma unroll
    for (int t=1;t<16;t++)
      #pragma unroll
      for (int s=0;s<16;s++){
        if (s<t) pv[t] += WN[t*17+s]*pv[s];
      }
    i32x4 o;
    o[0]=pk2(pv[0],pv[1]); o[1]=pk2(pv[2],pv[3]); o[2]=pk2(pv[4],pv[5]); o[3]=pk2(pv[6],pv[7]);
    *(i32x4*)(&pbb[l*24]) = o;
    o[0]=pk2(pv[8],pv[9]); o[1]=pk2(pv[10],pv[11]); o[2]=pk2(pv[12],pv[13]); o[3]=pk2(pv[14],pv[15]);
    *(i32x4*)(&pbb[l*24+8]) = o;
  }

  // ---- z-solve: (I-N)zloc = YhatV, lane = column i=l ----
  {
    float zz[16];
    #pragma unroll
    for (int t=0;t<16;t++) zz[t]=rhsb[t*68+l];
    #pragma unroll
    for (int t=1;t<16;t++)
      #pragma unroll
      for (int s=0;s<16;s++){
        if (s<t) zz[t] += WN[t*17+s]*zz[s];
      }
    i32x4 o;
    o[0]=pk2(zz[0],zz[1]); o[1]=pk2(zz[2],zz[3]); o[2]=pk2(zz[4],zz[5]); o[3]=pk2(zz[6],zz[7]);
    *(i32x4*)(&zbb[l*24]) = o;
    o[0]=pk2(zz[8],zz[9]); o[1]=pk2(zz[10],zz[11]); o[2]=pk2(zz[12],zz[13]); o[3]=pk2(zz[14],zz[15]);
    *(i32x4*)(&zbb[l*24+8]) = o;
  }
  asm volatile("s_waitcnt lgkmcnt(0)" ::: "memory");
  __builtin_amdgcn_sched_barrier(0);

  // ---- G = Rtil + Tb*P -> gtmp ; Yloc = Tb*zloc + Tk*V -> record strips ----
  {
    s16x8 wbf=zero8, wkf=zero8;
    if (g<2){
      wbf=*(const s16x8*)(&WB[c16*24 + 8*g]);
      wkf=*(const s16x8*)(&WK[c16*24 + 8*g]);
    }
    #pragma unroll
    for (int J=0;J<4;J++){
      s16x8 pfB=zero8, zfB=zero8;
      if (g<2){
        pfB=*(const s16x8*)(&pbb[(16*J+c16)*24 + 8*g]);
        zfB=*(const s16x8*)(&zbb[(16*J+c16)*24 + 8*g]);
      }
      f32x4 dG, dYl=zf4;
      #pragma unroll
      for (int e=0;e<4;e++) dG[e]=bf2f(RT[(4*g+e)*72 + 16*J + c16]);
      dG=MFMA32(wbf,pfB,dG);
      dYl=MFMA32(wbf,zfB,dYl);
      dYl=MFMA32(wkf,vf[J],dYl);
      #pragma unroll
      for (int e=0;e<4;e++) gtmp[(4*g+e)*68 + 16*J + c16]=dG[e];
      i32x2 o2; o2[0]=pk2(dYl[0],dYl[1]); o2[1]=pk2(dYl[2],dYl[3]);
      *(i32x2*)(rec + 10496 + (size_t)J*2560 + 2048 + (size_t)l*8) = o2;
    }
  }

  // ---- Q = P^T [Bbar;Kbar] tiles -> record Q A-frags; c = [Bbar;Kbar]^T [z;V] ----
  {
    s16x8 bk[4], pfr[4], bzv[4];
    #pragma unroll
    for (int nt=0;nt<4;nt++) bk[nt]=*(const s16x8*)(&BKL[(16*nt+c16)*40 + 8*g]);
    #pragma unroll
    for (int mt=0;mt<4;mt++)
      pfr[mt]= (g<2) ? *(const s16x8*)(&pbb[(16*mt+c16)*24 + 8*g]) : zero8;
    #pragma unroll
    for (int it=0;it<4;it++)
      bzv[it]= (g<2) ? *(const s16x8*)(&zbb[(16*it+c16)*24 + 8*g])
                     : *(const s16x8*)(&vbb[(16*it+c16)*24 + 8*(g-2)]);
    #pragma unroll
    for (int mt=0;mt<4;mt++){
      #pragma unroll
      for (int nt=0;nt<4;nt++){
        f32x4 dQ = MFMA32(pfr[mt], bk[nt], zf4);
        int kk = mt>>1, gq = ((mt&1)<<1) | (g>>1), jo = g&1;
        i32x2 o2; o2[0]=pk2(dQ[0],dQ[1]); o2[1]=pk2(dQ[2],dQ[3]);
        *(i32x2*)(rec + ((size_t)(kk*4+nt)*64 + (size_t)(c16 + 16*gq))*16 + 8*jo) = o2;
      }
    }
    #pragma unroll
    for (int jtp=0;jtp<4;jtp++){
      #pragma unroll
      for (int it=0;it<4;it++){
        f32x4 dc = MFMA32(bk[jtp], bzv[it], zf4);
        i32x2 o2; o2[0]=pk2(dc[0],dc[1]); o2[1]=pk2(dc[2],dc[3]);
        *(i32x2*)(rec + 10496 + (size_t)it*2560 + ((size_t)jtp*64 + l)*8) = o2;
      }
    }
  }

  // ---- G A-frags -> record ----
  #pragma unroll
  for (int kk=0;kk<2;kk++){
    f32x4 b0 = *(const f32x4*)(&gtmp[c16*68 + 32*kk + 8*g]);
    f32x4 b1 = *(const f32x4*)(&gtmp[c16*68 + 32*kk + 8*g + 4]);
    i32x4 o;
    o[0]=pk2(b0[0],b0[1]); o[1]=pk2(b0[2],b0[3]); o[2]=pk2(b1[0],b1[1]); o[3]=pk2(b1[2],b1[3]);
    *(i32x4*)(rec + 8192 + (size_t)(kk*64+l)*16) = o;
  }
}

// ---------------- serial scan: register-direct loads, 4 waves/block, depth-3 prefetch ----
__global__ __launch_bounds__(256, 1) void scan2_kernel(
    const char* __restrict__ recb, float* __restrict__ YB,
    const float* __restrict__ S0, float* __restrict__ dout){
  int bh=blockIdx.x;
  int tid=threadIdx.x, w=tid>>6, l=tid&63, c16=l&15, g=l>>4;

  __shared__ __align__(16) u16 ST[4][16*88];
  u16* STw = &ST[w][0];

  f32x4 Sreg[4];
  #pragma unroll
  for (int jt=0;jt<4;jt++)
    Sreg[jt] = *(const f32x4*)(S0 + (size_t)bh*4096 + (size_t)(16*w+c16)*64 + 16*jt + 4*g);
  #pragma unroll
  for (int jt=0;jt<4;jt++){
    i32x2 p; p[0]=pk2(Sreg[jt][0],Sreg[jt][1]); p[1]=pk2(Sreg[jt][2],Sreg[jt][3]);
    *(i32x2*)(&STw[c16*88 + 16*jt + 4*g]) = p;
  }

  const char* rb = recb + (size_t)(bh*64)*24576;
  float* yb0 = YB + (size_t)bh*65536;

#define DECLR(S) s16x8 qf##S[8]; s16x8 gf##S[2]; f32x4 pl##S[4]; i32x2 cf##S[4]; i32x2 yl##S;
#define LOADR(S, nc) do{ \
    const char* rp_ = rb + (size_t)(nc)*24576; \
    _Pragma("unroll") \
    for (int q_=0;q_<8;q_++) qf##S[q_] = *(const s16x8*)(rp_ + (size_t)q_*1024 + l*16); \
    gf##S[0] = *(const s16x8*)(rp_ + 8192 + (size_t)l*16); \
    gf##S[1] = *(const s16x8*)(rp_ + 9216 + (size_t)l*16); \
    _Pragma("unroll") \
    for (int jt_=0;jt_<4;jt_++) pl##S[jt_] = *(const f32x4*)(rp_ + 10240 + (size_t)(16*jt_+4*g)*4); \
    _Pragma("unroll") \
    for (int jt_=0;jt_<4;jt_++) cf##S[jt_] = *(const i32x2*)(rp_ + 10496 + (size_t)w*2560 + (size_t)(jt_*64+l)*8); \
    yl##S = *(const i32x2*)(rp_ + 10496 + (size_t)w*2560 + 2048 + (size_t)l*8); \
  }while(0)
#define STEP(S, ch) do{ \
    s16x8 sB0=*(const s16x8*)(&STw[c16*88 + 8*g]); \
    s16x8 sB1=*(const s16x8*)(&STw[c16*88 + 32 + 8*g]); \
    _Pragma("unroll") \
    for (int jt_=0;jt_<4;jt_++){ \
      f32x4 acc = cvt4(cf##S[jt_]); \
      acc = MFMA32(qf##S[jt_], sB0, acc); \
      acc = MFMA32(qf##S[4+jt_], sB1, acc); \
      _Pragma("unroll") \
      for (int e_=0;e_<4;e_++) acc[e_] = fmaf(pl##S[jt_][e_], Sreg[jt_][e_], acc[e_]); \
      Sreg[jt_]=acc; \
    } \
    _Pragma("unroll") \
    for (int jt_=0;jt_<4;jt_++){ \
      i32x2 p_; p_[0]=cvtpk(Sreg[jt_][0],Sreg[jt_][1]); p_[1]=cvtpk(Sreg[jt_][2],Sreg[jt_][3]); \
      *(i32x2*)(&STw[c16*88 + 16*jt_ + 4*g]) = p_; \
    } \
    f32x4 dy=cvt4(yl##S); \
    dy=MFMA32(gf##S[0],sB0,dy); dy=MFMA32(gf##S[1],sB1,dy); \
    { float* yb_ = yb0 + (size_t)(ch)*1024; \
      _Pragma("unroll") \
      for (int e_=0;e_<4;e_++) yb_[(size_t)(4*g+e_)*64 + 16*w + c16] = dy[e_]; } \
  }while(0)

  DECLR(A); DECLR(B); DECLR(C);
  LOADR(A, 0);
  LOADR(B, 1);
  LOADR(C, 2);

  // 64 chunks = 21 iterations x 3 + 1 epilogue
  #pragma unroll 1
  for (int ch=0; ch<63; ch+=3){
    STEP(A, ch);
    { int nc = ch+3; if (nc>63) nc=63; LOADR(A, nc); }
    STEP(B, ch+1);
    { int nc = ch+4; if (nc>63) nc=63; LOADR(B, nc); }
    STEP(C, ch+2);
    { int nc = ch+5; if (nc>63) nc=63; LOADR(C, nc); }
  }
  STEP(A, 63);
#undef DECLR
#undef LOADR
#undef STEP

  #pragma unroll
  for (int jt=0;jt<4;jt++)
    *(f32x4*)(dout + 2097152 + (size_t)bh*4096 + (size_t)(16*w+c16)*64 + 16*jt + 4*g) = Sreg[jt];
}

// ---------------- epilogue: groupnorm + bonus + gate -> bf16 ----------------
__global__ __launch_bounds__(256) void epi_kernel(char* ws, const float* lnw, const float* lnb)
{
  const float* YB=(const float*)(ws+OFF_YBUF);
  const u16* VEPI=(const u16*)(ws+OFF_VEPI);
  const float* DPp=(const float*)(ws+OFF_DP);
  const float* GB=(const float*)(ws+OFF_GBUF);
  u16* XGB=(u16*)(ws+OFF_XGB);
  int m=blockIdx.x, b=m>>10, t=m&1023;
  int tid=threadIdx.x, c0=tid*4, h=c0>>6, i0=c0&63;
  f32x4 y=*(const f32x4*)(YB + ((size_t)(b*16+h)*1024+t)*64 + i0);
  float s = y[0]+y[1]+y[2]+y[3];
  float ss= y[0]*y[0]+y[1]*y[1]+y[2]*y[2]+y[3]*y[3];
  #pragma unroll
  for (int mk=1;mk<16;mk<<=1){ s+=__shfl_xor(s,mk); ss+=__shfl_xor(ss,mk); }
  float mu=s*(1.0f/64.0f), var=ss*(1.0f/64.0f)-mu*mu;
  float inv=rsqrtf(var + 6.4e-4f);
  u16x4 v16=*(const u16x4*)(VEPI + ((size_t)(b*16+h)*1024+t)*64 + i0);
  float dp = DPp[(size_t)(b*16+h)*1024 + t];
  f32x4 gg=*(const f32x4*)(GB+(size_t)m*1024+c0);
  u16x4 outv;
  #pragma unroll
  for (int j=0;j<4;j++){
    float xn = (y[j]-mu)*inv*lnw[c0+j] + lnb[c0+j] + dp*bf2f(v16[j]);
    outv[j]=f2bf(xn*gg[j]);
  }
  *(u16x4*)(XGB+(size_t)m*1024+c0)=outv;
}

extern "C" void kernel_launch(void* const* d_in, const int* in_sizes, int n_in,
                              void* d_out, int out_size, void* d_ws, size_t ws_size,
                              hipStream_t stream) {
  const float* x      =(const float*)d_in[0];
  const float* S0     =(const float*)d_in[1];
  const float* vfirst =(const float*)d_in[2];
  const float* w0     =(const float*)d_in[3];
  const float* w1     =(const float*)d_in[4];
  const float* w2     =(const float*)d_in[5];
  const float* a0     =(const float*)d_in[6];
  const float* a1     =(const float*)d_in[7];
  const float* a2     =(const float*)d_in[8];
  const float* v0     =(const float*)d_in[9];
  const float* v1     =(const float*)d_in[10];
  const float* v2     =(const float*)d_in[11];
  const float* g1     =(const float*)d_in[12];
  const float* g2     =(const float*)d_in[13];
  const float* k_k    =(const float*)d_in[14];
  const float* k_a    =(const float*)d_in[15];
  const float* r_k    =(const float*)d_in[16];
  const float* Wq     =(const float*)d_in[17];
  const float* Wk     =(const float*)d_in[18];
  const float* Wv     =(const float*)d_in[19];
  const float* Wo     =(const float*)d_in[20];
  const float* ln_w   =(const float*)d_in[21];
  const float* ln_b   =(const float*)d_in[22];
  char* ws=(char*)d_ws;
  float* dout=(float*)d_out;

  prep_kernel<<<2048,256,0,stream>>>(ws,x,vfirst,w1,w2,a1,a2,v1,v2,g1,g2,Wq,Wk,Wv,Wo,dout);
  gemm_kernel<<<dim3(32,19),256,0,stream>>>(0,ws,w0,a0,v0,dout);
  gemm_kernel<<<dim3(32,32),256,0,stream>>>(1,ws,w0,a0,v0,dout);
  prep2_kernel<<<2048,256,0,stream>>>(ws,vfirst,k_k,k_a,r_k);
  pre_kernel<<<2048,64,0,stream>>>(ws);
  scan2_kernel<<<32,256,0,stream>>>(ws+OFF_SEQ, (float*)(ws+OFF_YBUF), S0, dout);
  epi_kernel<<<2048,256,0,stream>>>(ws,ln_w,ln_b);
  gemm_kernel<<<dim3(32,8),256,0,stream>>>(2,ws,w0,a0,v0,dout);
}